// Round 12
// baseline (55.781 us; speedup 1.0000x reference)
//
#include <hip/hip_runtime.h>
#include <hip/hip_bf16.h>

// B=64, N=8192. Output: concat(feats_final (B,N,2), feats_sparse (B,N,2)) f32.
// R12: occupancy-first. Weights prepped once into d_ws (f16, transposed,
// bias-folded) by a tiny kernel; main kernel holds them in REGISTERS per
// chunk (no weight LDS), LDS ~48 KB, __launch_bounds__(512,6) -> target
// 24 waves/CU (was 16). Conv3 output merged via LDS + coalesced stores.

#define BB 64
#define NN 8192
#define KWARM 64
#define TSEG 512
#define H 8
#define PCH 4
#define NCH 132           // (TSEG+2H)/PCH
#define CHK 256
#define NT 512
#define HST 40            // 80 B rows: bank-quad(row)=5r%8 bijective (b128 floor)

// d_ws ushort layout: [0,1024) wt1 [co][32] (k16=bias); [1024,6656) wt2
// [co][176] (k160=bias); [6656,7008) wt3 [2][176] (k160=bias).

using half8  = __attribute__((ext_vector_type(8))) _Float16;
using f32x16 = __attribute__((ext_vector_type(16))) float;

__device__ __forceinline__ half8 ld16(const ushort* p) {   // 16B load (LDS/global)
    return *reinterpret_cast<const half8*>(p);
}
__device__ __forceinline__ ushort f2h(float x) {
    _Float16 h = (_Float16)x;
    return __builtin_bit_cast(unsigned short, h);
}
__device__ __forceinline__ uint pk2rn(float a, float b) {  // 2x cvt RN + pack
    union { _Float16 h[2]; uint u; } r;
    r.h[0] = (_Float16)a; r.h[1] = (_Float16)b;
    return r.u;
}
__device__ __forceinline__ float h2f(ushort u) {
    return (float)__builtin_bit_cast(_Float16, u);
}

#define CSTV(RV, IV, AV) { float dd_ = RV*RV + IV*IV;                      \
    float iv_ = __builtin_amdgcn_rcpf(dd_);                                \
    float nr_ = -(AV) - RV*iv_;                                            \
    IV = 1.0f + IV*iv_; RV = nr_; }
#define GC(LRV, LIV, RRV, RIV, AV, MM, GR, GI) {                           \
    float Dr_ = LRV + RRV + (AV), Di_ = LIV + RIV - 1.0f;                  \
    float iv_ = __builtin_amdgcn_rcpf(Dr_*Dr_ + Di_*Di_);                  \
    GR = Dr_*iv_*(MM); GI = -Di_*iv_*(MM); }

// ---------------- kernel 0: weight prep (1 block) ----------------
__global__ __launch_bounds__(256) void prep_w(
    const float* __restrict__ w1, const float* __restrict__ b1,
    const float* __restrict__ w2, const float* __restrict__ b2,
    const float* __restrict__ w3, const float* __restrict__ b3,
    ushort* __restrict__ ws)
{
    const int t = threadIdx.x;
    for (int i = t; i < 1024; i += 256) {
        int co = i >> 5, k = i & 31;
        ushort v = 0;
        if (k < 10)       v = f2h(w1[co*10 + (k&1)*5 + (k>>1)]);
        else if (k == 16) v = f2h(b1[co]);
        ws[i] = v;
    }
    for (int i = t; i < 5632; i += 256) {
        int co = i / 176, k = i % 176;
        ushort v = 0;
        if (k < 160)       v = f2h(w2[co*160 + (k&31)*5 + (k>>5)]);
        else if (k == 160) v = f2h(b2[co]);
        ws[1024 + i] = v;
    }
    for (int i = t; i < 352; i += 256) {
        int co = i / 176, k = i % 176;
        ushort v = 0;
        if (k < 160)       v = f2h(w3[co*160 + (k&31)*5 + (k>>5)]);
        else if (k == 160) v = f2h(b3[co]);
        ws[6656 + i] = v;
    }
}

// ---------------- kernel 1: fused scan + conv ----------------
__global__ __launch_bounds__(NT, 6) void fused_kernel(
    const float* __restrict__ v,  const float* __restrict__ mask,
    const ushort* __restrict__ wsw,
    float* __restrict__ outF, float* __restrict__ fs)
{
    __shared__ __align__(16) ushort h1t[264 * HST];  // [row rel c-4][ci]; aliases sa
    __shared__ __align__(16) ushort h2t[260 * HST];  // [row rel c-2][ci]
    __shared__ __align__(16) uint   xsp[TSEG + 2*H + 8];
    __shared__ __align__(16) float2 co3s[CHK];
    __shared__ __align__(4) unsigned char mskb[TSEG];

    const int tid  = threadIdx.x;
    const int b    = blockIdx.y;
    const int s    = blockIdx.x * TSEG;
    const int base = s - H - KWARM;

    float* sa = reinterpret_cast<float*>(h1t);       // phase-A alias (2624 B)

    for (int i = tid; i < TSEG + 2*H + 2*KWARM; i += NT) {
        int g = base + i; g = min(max(g, 0), NN - 1);
        sa[i] = v[b * NN + g] - 2.0f;
    }
    __syncthreads();

    // ---- phase A: chains (threads 0..131); others zero the xsp pad ----
    if (tid < NCH) {
        const int e0 = s - H + PCH * tid;
        if (e0 >= 0 && e0 + PCH <= NN) {
            float4 mv = *reinterpret_cast<const float4*>(&mask[b * NN + e0]);
            float Lr, Li, Rr, Ri;
            const bool fast = (e0 - KWARM >= 0) && (e0 + 3 + KWARM <= NN - 1);
            if (fast) {
                const int i0 = e0 - KWARM - base;    // multiple of 4
                const float4* s4 = reinterpret_cast<const float4*>(sa);
                float4 cL = s4[i0 >> 2];
                float4 cR = s4[(i0 + 2*KWARM) >> 2];
                Lr = -cL.x; Li = 1.0f; Rr = -cR.w; Ri = 1.0f;
                CSTV(Lr, Li, cL.y); CSTV(Rr, Ri, cR.z);
                CSTV(Lr, Li, cL.z); CSTV(Rr, Ri, cR.y);
                CSTV(Lr, Li, cL.w); CSTV(Rr, Ri, cR.x);
                #pragma unroll
                for (int g = 1; g <= KWARM/4 - 1; ++g) {
                    float4 nL = s4[(i0 + 4*g) >> 2];
                    float4 nR = s4[(i0 + 2*KWARM - 4*g) >> 2];
                    CSTV(Lr, Li, nL.x); CSTV(Rr, Ri, nR.w);
                    CSTV(Lr, Li, nL.y); CSTV(Rr, Ri, nR.z);
                    CSTV(Lr, Li, nL.z); CSTV(Rr, Ri, nR.y);
                    CSTV(Lr, Li, nL.w); CSTV(Rr, Ri, nR.x);
                }
                CSTV(Lr, Li, sa[i0 + KWARM]);        // L at e0
                CSTV(Rr, Ri, sa[i0 + KWARM + 3]);    // R at e0+3
            } else {
                int j0 = max(e0 - KWARM, 0);
                Lr = -sa[j0 - base]; Li = 1.0f;
                for (int j = j0 + 1; j <= e0; ++j) CSTV(Lr, Li, sa[j - base]);
                int j1 = min(e0 + 3 + KWARM, NN - 1);
                Rr = -sa[j1 - base]; Ri = 1.0f;
                for (int j = j1 - 1; j >= e0 + 3; --j) CSTV(Rr, Ri, sa[j - base]);
            }
            float a0v = sa[e0 - base],     a1v = sa[e0 + 1 - base];
            float a2v = sa[e0 + 2 - base], a3v = sa[e0 + 3 - base];
            float L0r = Lr, L0i = Li;
            CSTV(Lr, Li, a1v); float L1r = Lr, L1i = Li;
            CSTV(Lr, Li, a2v); float L2r = Lr, L2i = Li;
            CSTV(Lr, Li, a3v); float L3r = Lr, L3i = Li;
            float g0r,g0i,g1r,g1i,g2r,g2i,g3r,g3i;
            GC(L3r, L3i, Rr, Ri, a3v, mv.w, g3r, g3i);
            CSTV(Rr, Ri, a2v); GC(L2r, L2i, Rr, Ri, a2v, mv.z, g2r, g2i);
            CSTV(Rr, Ri, a1v); GC(L1r, L1i, Rr, Ri, a1v, mv.y, g1r, g1i);
            CSTV(Rr, Ri, a0v); GC(L0r, L0i, Rr, Ri, a0v, mv.x, g0r, g0i);

            uint4 pk;
            pk.x = (uint)f2h(g0r) | ((uint)f2h(g0i) << 16);
            pk.y = (uint)f2h(g1r) | ((uint)f2h(g1i) << 16);
            pk.z = (uint)f2h(g2r) | ((uint)f2h(g2i) << 16);
            pk.w = (uint)f2h(g3r) | ((uint)f2h(g3i) << 16);
            *reinterpret_cast<uint4*>(&xsp[PCH * tid]) = pk;

            if (e0 >= s && e0 < s + TSEG) {
                float4 oa = make_float4(g0r, g0i, g1r, g1i);
                float4 ob = make_float4(g2r, g2i, g3r, g3i);
                size_t off = ((size_t)b * NN + e0) * 2;
                *reinterpret_cast<float4*>(&fs[off])     = oa;
                *reinterpret_cast<float4*>(&fs[off + 4]) = ob;
                uint mb = (mv.x > 0.5f ? 1u : 0u) | (mv.y > 0.5f ? 1u : 0u) << 8
                        | (mv.z > 0.5f ? 1u : 0u) << 16 | (mv.w > 0.5f ? 1u : 0u) << 24;
                *reinterpret_cast<uint*>(&mskb[e0 - s]) = mb;
            }
        } else {
            uint4 z = {0u, 0u, 0u, 0u};
            *reinterpret_cast<uint4*>(&xsp[PCH * tid]) = z;
        }
    } else if (tid < NCH + 8) {
        xsp[TSEG + 2*H + (tid - NCH)] = 0u;          // conv1 tail-tile pad
    }
    __syncthreads();
    // sa (aliased with h1t) dead from here.

    const int lane = tid & 63;
    const int wv   = tid >> 6;        // 0..7
    const int cn   = lane & 31;
    const int kh   = lane >> 5;
    const int kh4  = 4 * kh;

    // ones fragment built in-register: k-slice {1,0,...} on kh=0 half
    union { half8 v8; uint u[4]; } on;
    on.u[0] = kh ? 0u : 0x3C00u; on.u[1] = 0u; on.u[2] = 0u; on.u[3] = 0u;
    const half8 onesF = on.v8;

    const ushort* w1g = wsw + cn * 32 + 8 * kh;
    const ushort* w2g = wsw + 1024 + cn * 176 + 8 * kh;
    const ushort* w3g = wsw + 6656 + ((cn < 2) ? cn : 0) * 176 + 8 * kh;

    for (int ch = 0; ch < TSEG / CHK; ++ch) {
        const int cr = ch * CHK;

        // ---- conv1: weights from L2 -> regs; 9 tiles (+wave0 tail) ----
        {
            half8 wA1  = ld16(w1g);
            half8 wA1b = ld16(w1g + 16);
            #pragma unroll
            for (int pass = 0; pass < 2; ++pass) {
                int t = (pass == 0) ? wv : ((wv == 0) ? 8 : -1);
                if (t >= 0) {
                    int tb1 = (t < 8) ? 32*t : 232;
                    int mi  = cr + 2 + tb1 + cn;
                    union { half8 v8; uint u[4]; } B;
                    B.u[0] = xsp[mi + kh4];     B.u[1] = xsp[mi + kh4 + 1];
                    B.u[2] = xsp[mi + kh4 + 2]; B.u[3] = xsp[mi + kh4 + 3];
                    f32x16 a1 = {};
                    a1 = __builtin_amdgcn_mfma_f32_32x32x16_f16(wA1,  B.v8,  a1, 0, 0, 0);
                    a1 = __builtin_amdgcn_mfma_f32_32x32x16_f16(wA1b, onesF, a1, 0, 0, 0);
                    int row = tb1 + cn;
                    int gp  = s + cr - 4 + row;
                    bool ok = (gp >= 0) && (gp < NN);
                    ushort* rp = &h1t[row * HST + kh4];
                    #pragma unroll
                    for (int q = 0; q < 4; ++q) {
                        uint lo = pk2rn(fmaxf(a1[4*q+0], 0.f), fmaxf(a1[4*q+1], 0.f));
                        uint hi = pk2rn(fmaxf(a1[4*q+2], 0.f), fmaxf(a1[4*q+3], 0.f));
                        *reinterpret_cast<uint2*>(rp + 8*q) =
                            make_uint2(ok ? lo : 0u, ok ? hi : 0u);
                    }
                }
            }
        }
        __syncthreads();

        // ---- conv2: weights from L2 -> regs per chunk; 9 tiles (+wave1 tail)
        {
            half8 wA2[11];
            #pragma unroll
            for (int q = 0; q < 11; ++q) wA2[q] = ld16(w2g + 16*q);
            #pragma unroll
            for (int pass = 0; pass < 2; ++pass) {
                int t = (pass == 0) ? wv : ((wv == 1) ? 8 : -1);
                if (t >= 0) {
                    int tb2 = (t < 8) ? 32*t : 228;
                    f32x16 acc = {};
                    #pragma unroll
                    for (int q = 0; q < 10; ++q) {
                        int kidx = 16*q + 8*kh;
                        half8 Bf = ld16(&h1t[(tb2 + cn + (kidx >> 5))*HST + (kidx & 31)]);
                        acc = __builtin_amdgcn_mfma_f32_32x32x16_f16(wA2[q], Bf, acc, 0, 0, 0);
                    }
                    acc = __builtin_amdgcn_mfma_f32_32x32x16_f16(wA2[10], onesF, acc, 0, 0, 0);
                    int row = tb2 + cn;
                    int gp  = s + cr - 2 + row;
                    bool ok = (gp >= 0) && (gp < NN);
                    ushort* rp = &h2t[row * HST + kh4];
                    #pragma unroll
                    for (int q = 0; q < 4; ++q) {
                        uint lo = pk2rn(fmaxf(acc[4*q+0], 0.f), fmaxf(acc[4*q+1], 0.f));
                        uint hi = pk2rn(fmaxf(acc[4*q+2], 0.f), fmaxf(acc[4*q+3], 0.f));
                        *reinterpret_cast<uint2*>(rp + 8*q) =
                            make_uint2(ok ? lo : 0u, ok ? hi : 0u);
                    }
                }
            }
        }
        __syncthreads();

        // ---- conv3: weights from L2; 8 tiles; result -> co3s (f32 LDS) ----
        {
            half8 wA3[11];
            #pragma unroll
            for (int q = 0; q < 11; ++q) wA3[q] = ld16(w3g + 16*q);
            const int tb3 = 32 * wv;
            f32x16 a3 = {};
            #pragma unroll
            for (int q = 0; q < 10; ++q) {
                int kidx = 16*q + 8*kh;
                half8 Bf = ld16(&h2t[(tb3 + cn + (kidx >> 5))*HST + (kidx & 31)]);
                a3 = __builtin_amdgcn_mfma_f32_32x32x16_f16(wA3[q], Bf, a3, 0, 0, 0);
            }
            a3 = __builtin_amdgcn_mfma_f32_32x32x16_f16(wA3[10], onesF, a3, 0, 0, 0);
            if (kh == 0) co3s[tb3 + cn] = make_float2(a3[0], a3[1]);
        }
        __syncthreads();

        // ---- merge: coalesced float2 store of outF for this chunk ----
        if (tid < CHK) {
            int p = cr + tid;
            float2 cv = co3s[tid];
            uint  xp  = xsp[H + p];
            bool  m   = mskb[p] != 0;
            float ox  = m ? h2f((ushort)(xp & 0xffffu)) : cv.x;
            float oy  = m ? h2f((ushort)(xp >> 16))     : cv.y;
            *reinterpret_cast<float2*>(&outF[((size_t)b*NN + s + p)*2]) =
                make_float2(ox, oy);
        }
        // no barrier: next conv1 writes h1t (last read 2 barriers ago);
        // next conv3 write of co3s is separated by conv1+conv2 barriers.
    }
}

extern "C" void kernel_launch(void* const* d_in, const int* in_sizes, int n_in,
                              void* d_out, int out_size, void* d_ws, size_t ws_size,
                              hipStream_t stream) {
    const float* v    = (const float*)d_in[0];
    const float* mask = (const float*)d_in[1];
    const float* w1   = (const float*)d_in[2];
    const float* b1   = (const float*)d_in[3];
    const float* w2   = (const float*)d_in[4];
    const float* b2   = (const float*)d_in[5];
    const float* w3   = (const float*)d_in[6];
    const float* b3   = (const float*)d_in[7];

    float*  outF = (float*)d_out;                  // feats_final (B,N,2)
    float*  fs   = outF + (size_t)BB * NN * 2;     // feats_sparse (B,N,2)
    ushort* ws16 = (ushort*)d_ws;

    prep_w<<<dim3(1), 256, 0, stream>>>(w1, b1, w2, b2, w3, b3, ws16);

    dim3 g(NN / TSEG, BB);                         // 16 x 64 = 1024 blocks
    fused_kernel<<<g, NT, 0, stream>>>(v, mask, ws16, outF, fs);
}

// Round 14
// 34.268 us; speedup vs baseline: 1.6278x; 1.6278x over previous
//
#include <hip/hip_runtime.h>
#include <hip/hip_bf16.h>

// B=64, N=8192. Output: concat(feats_final (B,N,2), feats_sparse (B,N,2)) f32.
// R14 = R13 (barrier-free wave-private conv) + ordering fixes:
//   - h-tile LDS reads use uint2 (same type as stores) so the scheduler's
//     alias analysis sees the same-wave ds_write->ds_read dependence
//     (R13's half8 reads vs uint2 writes let TBAA reorder them -> NaN).
//   - asm memory fences between conv phases (belt and braces).
// HW note: per-wave DS ops execute in issue order at the LDS pipe, so
// compiler-level ordering is sufficient; no barrier needed.

#define BB 64
#define NN 8192
#define KWARM 64
#define TSEG 1024
#define H 8
#define PCH 4
#define NCH 260
#define STG0 320
#define CHK 256
#define NT 512
#define HST 40            // 80 B rows: bank-quad(row)=5r%8 bijective

using half8  = __attribute__((ext_vector_type(8))) _Float16;
using f32x16 = __attribute__((ext_vector_type(16))) float;

#define FENCE() asm volatile("" ::: "memory")

__device__ __forceinline__ half8 ld16(const ushort* p) {   // ds_read_b128 (weights)
    return *reinterpret_cast<const half8*>(p);
}
__device__ __forceinline__ half8 ldh8(const ushort* p) {   // 2x ds_read_b64, uint2-typed
    const uint2* q = reinterpret_cast<const uint2*>(p);
    uint2 a = q[0], c = q[1];
    union { uint u[4]; half8 v; } r;
    r.u[0] = a.x; r.u[1] = a.y; r.u[2] = c.x; r.u[3] = c.y;
    return r.v;
}
__device__ __forceinline__ ushort f2h(float x) {
    _Float16 h = (_Float16)x;
    return __builtin_bit_cast(unsigned short, h);
}
__device__ __forceinline__ uint pk2rn(float a, float b) {  // 2x cvt RN + pack
    union { _Float16 h[2]; uint u; } r;
    r.h[0] = (_Float16)a; r.h[1] = (_Float16)b;
    return r.u;
}

#define CSTV(RV, IV, AV) { float dd_ = RV*RV + IV*IV;                      \
    float iv_ = __builtin_amdgcn_rcpf(dd_);                                \
    float nr_ = -(AV) - RV*iv_;                                            \
    IV = 1.0f + IV*iv_; RV = nr_; }
#define GC(LRV, LIV, RRV, RIV, AV, MM, GR, GI) {                           \
    float Dr_ = LRV + RRV + (AV), Di_ = LIV + RIV - 1.0f;                  \
    float iv_ = __builtin_amdgcn_rcpf(Dr_*Dr_ + Di_*Di_);                  \
    GR = Dr_*iv_*(MM); GI = -Di_*iv_*(MM); }

__global__ __launch_bounds__(NT, 4) void fused_kernel(
    const float* __restrict__ v,  const float* __restrict__ mask,
    const float* __restrict__ w1, const float* __restrict__ b1,
    const float* __restrict__ w2, const float* __restrict__ b2,
    const float* __restrict__ w3, const float* __restrict__ b3,
    float* __restrict__ outF, float* __restrict__ fs)
{
    __shared__ __align__(16) ushort h1w_all[8][40 * HST]; // per-wave; aliases sa
    __shared__ __align__(16) ushort h2w_all[8][36 * HST]; // per-wave
    __shared__ __align__(16) ushort wt1c[32 * 32];   // [co][k]; k16=bias
    __shared__ __align__(16) ushort wt2c[32 * 176];  // [co][k=kk*32+ci]; k160=bias
    __shared__ __align__(16) ushort wt3c[2 * 176];   // k160=bias
    __shared__ __align__(16) uint   xsp[TSEG + 2*H + 8];
    __shared__ __align__(4) unsigned char mskb[TSEG];

    const int tid  = threadIdx.x;
    const int b    = blockIdx.y;
    const int s    = blockIdx.x * TSEG;
    const int base = s - H - KWARM;

    float* sa = reinterpret_cast<float*>(h1w_all);   // phase-A alias (4672 B)

    for (int i = tid; i < TSEG + 2*H + 2*KWARM; i += NT) {
        int g = base + i; g = min(max(g, 0), NN - 1);
        sa[i] = v[b * NN + g] - 2.0f;
    }
    __syncthreads();

    // ---- phase A: chains (0..259) || weight staging (320..511) ----
    if (tid < NCH) {
        const int e0 = s - H + PCH * tid;
        if (e0 >= 0 && e0 + PCH <= NN) {
            float4 mv = *reinterpret_cast<const float4*>(&mask[b * NN + e0]);
            float Lr, Li, Rr, Ri;
            const bool fast = (e0 - KWARM >= 0) && (e0 + 3 + KWARM <= NN - 1);
            if (fast) {
                const int i0 = e0 - KWARM - base;    // = 4*tid
                const float4* s4 = reinterpret_cast<const float4*>(sa);
                float4 cL = s4[i0 >> 2];
                float4 cR = s4[(i0 + 2*KWARM) >> 2];
                Lr = -cL.x; Li = 1.0f; Rr = -cR.w; Ri = 1.0f;
                CSTV(Lr, Li, cL.y); CSTV(Rr, Ri, cR.z);
                CSTV(Lr, Li, cL.z); CSTV(Rr, Ri, cR.y);
                CSTV(Lr, Li, cL.w); CSTV(Rr, Ri, cR.x);
                #pragma unroll
                for (int g = 1; g <= KWARM/4 - 1; ++g) {
                    float4 nL = s4[(i0 + 4*g) >> 2];
                    float4 nR = s4[(i0 + 2*KWARM - 4*g) >> 2];
                    CSTV(Lr, Li, nL.x); CSTV(Rr, Ri, nR.w);
                    CSTV(Lr, Li, nL.y); CSTV(Rr, Ri, nR.z);
                    CSTV(Lr, Li, nL.z); CSTV(Rr, Ri, nR.y);
                    CSTV(Lr, Li, nL.w); CSTV(Rr, Ri, nR.x);
                }
                CSTV(Lr, Li, sa[i0 + KWARM]);        // L at e0
                CSTV(Rr, Ri, sa[i0 + KWARM + 3]);    // R at e0+3
            } else {
                int j0 = max(e0 - KWARM, 0);
                Lr = -sa[j0 - base]; Li = 1.0f;
                for (int j = j0 + 1; j <= e0; ++j) CSTV(Lr, Li, sa[j - base]);
                int j1 = min(e0 + 3 + KWARM, NN - 1);
                Rr = -sa[j1 - base]; Ri = 1.0f;
                for (int j = j1 - 1; j >= e0 + 3; --j) CSTV(Rr, Ri, sa[j - base]);
            }
            float a0v = sa[e0 - base],     a1v = sa[e0 + 1 - base];
            float a2v = sa[e0 + 2 - base], a3v = sa[e0 + 3 - base];
            float L0r = Lr, L0i = Li;
            CSTV(Lr, Li, a1v); float L1r = Lr, L1i = Li;
            CSTV(Lr, Li, a2v); float L2r = Lr, L2i = Li;
            CSTV(Lr, Li, a3v); float L3r = Lr, L3i = Li;
            float g0r,g0i,g1r,g1i,g2r,g2i,g3r,g3i;
            GC(L3r, L3i, Rr, Ri, a3v, mv.w, g3r, g3i);
            CSTV(Rr, Ri, a2v); GC(L2r, L2i, Rr, Ri, a2v, mv.z, g2r, g2i);
            CSTV(Rr, Ri, a1v); GC(L1r, L1i, Rr, Ri, a1v, mv.y, g1r, g1i);
            CSTV(Rr, Ri, a0v); GC(L0r, L0i, Rr, Ri, a0v, mv.x, g0r, g0i);

            uint4 pk;
            pk.x = (uint)f2h(g0r) | ((uint)f2h(g0i) << 16);
            pk.y = (uint)f2h(g1r) | ((uint)f2h(g1i) << 16);
            pk.z = (uint)f2h(g2r) | ((uint)f2h(g2i) << 16);
            pk.w = (uint)f2h(g3r) | ((uint)f2h(g3i) << 16);
            *reinterpret_cast<uint4*>(&xsp[PCH * tid]) = pk;

            if (e0 >= s && e0 < s + TSEG) {
                float4 oa = make_float4(g0r, g0i, g1r, g1i);
                float4 ob = make_float4(g2r, g2i, g3r, g3i);
                size_t off = ((size_t)b * NN + e0) * 2;
                *reinterpret_cast<float4*>(&fs[off])       = oa;
                *reinterpret_cast<float4*>(&fs[off + 4])   = ob;
                *reinterpret_cast<float4*>(&outF[off])     = oa;   // default: fs
                *reinterpret_cast<float4*>(&outF[off + 4]) = ob;
                uint mb = (mv.x > 0.5f ? 1u : 0u) | (mv.y > 0.5f ? 1u : 0u) << 8
                        | (mv.z > 0.5f ? 1u : 0u) << 16 | (mv.w > 0.5f ? 1u : 0u) << 24;
                *reinterpret_cast<uint*>(&mskb[e0 - s]) = mb;
            }
        } else {
            uint4 z = {0u, 0u, 0u, 0u};
            *reinterpret_cast<uint4*>(&xsp[PCH * tid]) = z;
        }
    } else if (tid >= STG0) {
        const int t0 = tid - STG0;                   // 192 staging threads
        for (int i = t0; i < 1024; i += 192) {       // wt1c [co][32]
            int co = i >> 5, k = i & 31;
            ushort val = 0;
            if (k < 10)       val = f2h(w1[co*10 + (k&1)*5 + (k>>1)]);
            else if (k == 16) val = f2h(b1[co]);
            wt1c[i] = val;
        }
        for (int i = t0; i < 5632; i += 192) {       // wt2c [co][176]
            int co = i / 176, k = i % 176;
            ushort val = 0;
            if (k < 160)       val = f2h(w2[co*160 + (k&31)*5 + (k>>5)]);
            else if (k == 160) val = f2h(b2[co]);
            wt2c[i] = val;
        }
        for (int i = t0; i < 352; i += 192) {        // wt3c [2][176]
            int co = i / 176, k = i % 176;
            ushort val = 0;
            if (k < 160)       val = f2h(w3[co*160 + (k&31)*5 + (k>>5)]);
            else if (k == 160) val = f2h(b3[co]);
            wt3c[i] = val;
        }
        if (t0 < 8) xsp[TSEG + 2*H + t0] = 0u;       // conv1 tail pad
    }
    __syncthreads();
    // sa (aliased with h1w_all) dead from here. LAST barrier in the kernel.

    const int lane = tid & 63;
    const int wv   = tid >> 6;        // 0..7
    const int cn   = lane & 31;
    const int kh   = lane >> 5;
    const int kh4  = 4 * kh;

    // ones fragment in-register: k-slice {1,0,...} on kh=0 half
    union { half8 v8; uint u[4]; } on;
    on.u[0] = kh ? 0u : 0x3C00u; on.u[1] = 0u; on.u[2] = 0u; on.u[3] = 0u;
    const half8 onesF = on.v8;

    // persistent weight A-fragments (from LDS, loop-invariant)
    half8 wA1  = ld16(&wt1c[cn * 32 + 8 * kh]);
    half8 wA1b = ld16(&wt1c[cn * 32 + 16 + 8 * kh]);
    half8 wA2[11];
    #pragma unroll
    for (int t = 0; t < 11; ++t) wA2[t] = ld16(&wt2c[cn*176 + 16*t + 8*kh]);

    ushort* h1w = h1w_all[wv];        // private: rows 0..39 ~ pos p0-4+r
    ushort* h2w = h2w_all[wv];        // private: rows 0..35 ~ pos p0-2+r

    for (int ch = 0; ch < TSEG / CHK; ++ch) {
        const int p0 = ch * CHK + wv * 32;   // this wave's output base (rel s)

        // ---- conv1: tiles t1=0,8 -> h1w rows 0..39 (overlap identical) ----
        #pragma unroll
        for (int ti = 0; ti < 2; ++ti) {
            const int t1 = 8 * ti;
            int mi = p0 + 2 + t1 + cn;
            union { half8 v8; uint u[4]; } B;
            if (kh == 0) { B.u[0]=xsp[mi];   B.u[1]=xsp[mi+1];
                           B.u[2]=xsp[mi+2]; B.u[3]=xsp[mi+3]; }
            else         { B.u[0]=xsp[mi+4]; B.u[1]=0; B.u[2]=0; B.u[3]=0; }
            f32x16 a1 = {};
            a1 = __builtin_amdgcn_mfma_f32_32x32x16_f16(wA1,  B.v8,  a1, 0, 0, 0);
            a1 = __builtin_amdgcn_mfma_f32_32x32x16_f16(wA1b, onesF, a1, 0, 0, 0);
            int rl = t1 + cn;
            int gp = s + p0 - 4 + rl;
            bool ok = (gp >= 0) && (gp < NN);
            ushort* rp = &h1w[rl * HST + kh4];
            #pragma unroll
            for (int q = 0; q < 4; ++q) {
                uint lo = pk2rn(fmaxf(a1[4*q+0], 0.f), fmaxf(a1[4*q+1], 0.f));
                uint hi = pk2rn(fmaxf(a1[4*q+2], 0.f), fmaxf(a1[4*q+3], 0.f));
                *reinterpret_cast<uint2*>(rp + 8*q) =
                    make_uint2(ok ? lo : 0u, ok ? hi : 0u);
            }
        }
        FENCE();   // order h1w writes before conv2 reads (same-wave, no barrier)

        // ---- conv2: tiles t2=0,4 -> h2w rows 0..35 (overlap identical) ----
        #pragma unroll
        for (int ti = 0; ti < 2; ++ti) {
            const int t2 = 4 * ti;
            f32x16 acc = {};
            #pragma unroll
            for (int q = 0; q < 10; ++q) {
                int kidx = 16*q + 8*kh;
                half8 Bf = ldh8(&h1w[(t2 + cn + (kidx >> 5))*HST + (kidx & 31)]);
                acc = __builtin_amdgcn_mfma_f32_32x32x16_f16(wA2[q], Bf, acc, 0, 0, 0);
            }
            acc = __builtin_amdgcn_mfma_f32_32x32x16_f16(wA2[10], onesF, acc, 0, 0, 0);
            int rl = t2 + cn;
            int gp = s + p0 - 2 + rl;
            bool ok = (gp >= 0) && (gp < NN);
            ushort* rp = &h2w[rl * HST + kh4];
            #pragma unroll
            for (int q = 0; q < 4; ++q) {
                uint lo = pk2rn(fmaxf(acc[4*q+0], 0.f), fmaxf(acc[4*q+1], 0.f));
                uint hi = pk2rn(fmaxf(acc[4*q+2], 0.f), fmaxf(acc[4*q+3], 0.f));
                *reinterpret_cast<uint2*>(rp + 8*q) =
                    make_uint2(ok ? lo : 0u, ok ? hi : 0u);
            }
        }
        FENCE();   // order h2w writes before conv3 reads

        // ---- conv3: one tile; kh=0 lanes store !mask positions ----
        {
            f32x16 a3 = {};
            const int wb = ((cn < 2) ? cn : 0) * 176;
            #pragma unroll
            for (int q = 0; q < 10; ++q) {
                int kidx = 16*q + 8*kh;
                half8 z = {};
                half8 Af = (cn < 2) ? ld16(&wt3c[wb + 16*q + 8*kh]) : z;
                half8 Bf = ldh8(&h2w[(cn + (kidx >> 5))*HST + (kidx & 31)]);
                a3 = __builtin_amdgcn_mfma_f32_32x32x16_f16(Af, Bf, a3, 0, 0, 0);
            }
            {
                half8 z = {};
                half8 Af = (cn < 2) ? ld16(&wt3c[wb + 160 + 8*kh]) : z;
                a3 = __builtin_amdgcn_mfma_f32_32x32x16_f16(Af, onesF, a3, 0, 0, 0);
            }
            if (kh == 0) {
                int p = p0 + cn;
                if (!mskb[p]) {
                    *reinterpret_cast<float2*>(&outF[((size_t)b*NN + s + p)*2]) =
                        make_float2(a3[0], a3[1]);
                }
            }
        }
        FENCE();   // order conv3 reads before next chunk's h1w/h2w writes (WAR)
    }
}

extern "C" void kernel_launch(void* const* d_in, const int* in_sizes, int n_in,
                              void* d_out, int out_size, void* d_ws, size_t ws_size,
                              hipStream_t stream) {
    const float* v    = (const float*)d_in[0];
    const float* mask = (const float*)d_in[1];
    const float* w1   = (const float*)d_in[2];
    const float* b1   = (const float*)d_in[3];
    const float* w2   = (const float*)d_in[4];
    const float* b2   = (const float*)d_in[5];
    const float* w3   = (const float*)d_in[6];
    const float* b3   = (const float*)d_in[7];

    float* outF = (float*)d_out;                  // feats_final (B,N,2)
    float* fs   = outF + (size_t)BB * NN * 2;     // feats_sparse (B,N,2)

    dim3 g(NN / TSEG, BB);                        // 8 x 64 = 512 blocks
    fused_kernel<<<g, NT, 0, stream>>>(v, mask, w1, b1, w2, b2, w3, b3, outF, fs);
}